// Round 14
// baseline (3935.500 us; speedup 1.0000x reference)
//
#include <hip/hip_runtime.h>
#include <stdint.h>

#define B_ 256
#define T_ 512
#define F_ 128
#define U_ 256
#define H_ 64
#define G4U 1024

typedef __attribute__((ext_vector_type(8))) short short8;
typedef __attribute__((ext_vector_type(4))) float f32x4;
typedef unsigned long long ull;

// LDS-only barrier: NO vmcnt drain.
#define BARRIER_LDS() asm volatile("s_waitcnt lgkmcnt(0)\ns_barrier" ::: "memory")

__device__ __forceinline__ uint16_t f2bf(float f) {
  uint32_t u = __builtin_bit_cast(uint32_t, f);
  u += 0x7fffu + ((u >> 16) & 1u);
  return (uint16_t)(u >> 16);
}
__device__ __forceinline__ float frcp(float x) {
  float r;
  asm volatile("v_rcp_f32 %0, %1" : "=v"(r) : "v"(x));
  return r;
}
__device__ __forceinline__ float sigm(float z) {   // v_exp + v_rcp fast path
  return frcp(1.0f + __expf(-z));
}
__device__ __forceinline__ ull ald(const ull* p) {
  return __hip_atomic_load(p, __ATOMIC_RELAXED, __HIP_MEMORY_SCOPE_AGENT);
}

// ---------------------------------------------------------------------------
// xz_pre (unchanged, proven ~17us/dispatch): xz = bias + x_t@kernel,
// f32 in MFMA C-layout: xz[(bg*L+tt)*16384 + (wd*4+q)*256 + lane*4 + r]
//   = z[row=(lane>>4)*4+r][col = q*256 + wd*16 + (lane&15)]
// ---------------------------------------------------------------------------
__global__ __launch_bounds__(256, 1) void xz_pre(
    const float* __restrict__ x, const float* __restrict__ kern,
    const float* __restrict__ bias, float* __restrict__ xz,
    int t0, int L)
{
  const int tid  = threadIdx.x;
  const int lane = tid & 63;
  const int q    = tid >> 6;
  const int il   = lane & 15;
  const int bx   = blockIdx.x;
  const int bg   = bx & 15;
  const int hp   = (bx >> 4) & 1;
  const int tc   = bx >> 5;

  __shared__ __align__(16) uint16_t kern_lds[8192 * 8];     // 128 KB
  __shared__ __align__(16) uint16_t x_stage[2][4][64][8];   // 8 KB dbuf

  for (int s = 0; s < 32; ++s) {
    const int slot = tid + s * 256;
    const int l = slot & 63, kt = (slot >> 6) & 3, ctl = (slot >> 8) & 7, qq = slot >> 11;
    const int col = qq * 256 + (hp * 8 + ctl) * 16 + (l & 15);
    const int kb  = kt * 32 + (l >> 4) * 8;
    short8 v;
    #pragma unroll
    for (int j = 0; j < 8; ++j)
      v[j] = (short)f2bf(kern[(size_t)(kb + j) * G4U + col]);
    *(short8*)&kern_lds[(size_t)slot * 8] = v;
  }
  float bias_r[8];
  #pragma unroll
  for (int ctl = 0; ctl < 8; ++ctl)
    bias_r[ctl] = bias[q * 256 + (hp * 8 + ctl) * 16 + il];

  const int xrow = tid & 15, xfb = (tid >> 4) * 8;
  const int xs_kt = xfb >> 5, xs_l = ((xfb >> 3) & 3) * 16 + xrow;

  float xv[8];
  {
    const float* p = x + ((size_t)(bg * 16 + xrow) * T_ + (t0 + tc * 16)) * F_ + xfb;
    #pragma unroll
    for (int j = 0; j < 8; ++j) xv[j] = p[j];
  }
  __syncthreads();

  for (int tt2 = 0; tt2 < 16; ++tt2) {
    const int t = t0 + tc * 16 + tt2;
    const int bb = tt2 & 1;
    {
      uint16_t* d = &x_stage[bb][xs_kt][xs_l][0];
      #pragma unroll
      for (int j = 0; j < 8; ++j) d[j] = f2bf(xv[j]);
    }
    BARRIER_LDS();
    {
      const int tn = (tt2 < 15) ? t + 1 : t;
      const float* p = x + ((size_t)(bg * 16 + xrow) * T_ + tn) * F_ + xfb;
      #pragma unroll
      for (int j = 0; j < 8; ++j) xv[j] = p[j];
    }
    f32x4 acc[8];
    #pragma unroll
    for (int ctl = 0; ctl < 8; ++ctl)
      acc[ctl] = (f32x4){bias_r[ctl], bias_r[ctl], bias_r[ctl], bias_r[ctl]};
    #pragma unroll
    for (int kt = 0; kt < 4; ++kt) {
      short8 a = *(const short8*)&x_stage[bb][kt][lane][0];
      #pragma unroll
      for (int ctl = 0; ctl < 8; ++ctl) {
        short8 b = *(const short8*)&kern_lds[(size_t)(((q * 8 + ctl) * 4 + kt) * 64 + lane) * 8];
        acc[ctl] = __builtin_amdgcn_mfma_f32_16x16x32_bf16(a, b, acc[ctl], 0, 0, 0);
      }
    }
    float* ob = xz + (size_t)(bg * L + (t - t0)) * 16384;
    #pragma unroll
    for (int ctl = 0; ctl < 8; ++ctl) {
      const int wd = hp * 8 + ctl;
      *(f32x4*)(ob + (size_t)(wd * 4 + q) * 256 + lane * 4) = acc[ctl];
    }
  }
}

// ---------------------------------------------------------------------------
// lstm_phase v3.1: IDENTICAL to R13 except __launch_bounds__(1024, 1).
// R13 lesson: (1024, 4) acted as min-4-BLOCKS/CU -> 16 waves/SIMD -> 128-reg
// per-wave budget -> wf spilled to scratch (VGPR_Count=64, 7.3us/step).
// (1024, 1): 1 block/CU -> 4 waves/SIMD -> 512-reg budget; wf[4][8] (128
// regs) + acc + zcur + addressing ~200 regs stays resident.
// Design: ONE WG per bg, 16 waves; wave w owns 16 units x all 4 gates ->
// ENTIRE rec_kernel in registers (16 x 32 KB = 512 KB); zero B-operand LDS;
// single pass/step (32 MFMA/wave); LDS/step = 128 KB A-broadcast; one
// barrier/step; LDS total 16 KB.
// ---------------------------------------------------------------------------
__global__ __launch_bounds__(1024, 1) void lstm_phase(
    const float* __restrict__ rker, uint16_t* __restrict__ seq,
    const float* __restrict__ xz, float* __restrict__ cstbuf,
    int t0, int L)
{
  const int tid  = threadIdx.x;
  const int lane = tid & 63;
  const int w    = tid >> 6;          // 0..15
  const int il   = lane & 15;
  const int rg   = lane >> 4;
  const int bg   = blockIdx.x;

  __shared__ __align__(16) uint16_t h_stage[2][8][64][8];   // 16 KB dbuf

  // ---- entire rec slice in VGPRs: wf[q][kt], col = q*256 + w*16 + il ----
  short8 wf[4][8];
  #pragma unroll
  for (int q = 0; q < 4; ++q) {
    const int col = q * 256 + w * 16 + il;
    #pragma unroll
    for (int kt = 0; kt < 8; ++kt) {
      short8 v;
      #pragma unroll
      for (int j = 0; j < 8; ++j)
        v[j] = (short)f2bf(rker[(size_t)(kt * 32 + rg * 8 + j) * G4U + col]);
      wf[q][kt] = v;
    }
  }

  // own unit constants (h write): u = w*16+il
  const int u   = w * 16 + il;
  const int kta = u >> 5, ga = ((u & 31) >> 3) * 16, posa = u & 7;

  // flat ull copy role (seq <-> h_stage): 1024 x 8B = 8 KB
  const int s_kt  = tid >> 7;
  const int s_rem = tid & 127;
  const int s_l   = s_rem >> 1;
  const int s_p0  = (s_rem & 1) * 4;
  const int s_row = s_l & 15;
  const int s_u0  = s_kt * 32 + (s_l >> 4) * 8 + s_p0;
  uint16_t* const seqrow = seq + (size_t)(bg * 16 + s_row) * T_ * U_ + s_u0;

  float cst[4];
  if (t0 == 0) {
    #pragma unroll
    for (int j = 0; j < 4; ++j) cst[j] = 0.f;
    ((ull*)h_stage)[1024 + tid] = 0;   // zero buf[1] (= h_{-1})
  } else {
    #pragma unroll
    for (int j = 0; j < 4; ++j)
      cst[j] = cstbuf[(size_t)(bg * 16 + rg * 4 + j) * U_ + u];
    // h_{t0-1} -> buf[(t0-1)&1] = buf[1] (t0 multiple of L, L even)
    *(ull*)&h_stage[1][s_kt][s_l][s_p0] =
        *(const ull*)(seqrow + (size_t)(t0 - 1) * U_);
  }
  __syncthreads();

  const float* const pz = xz + (size_t)bg * L * 16384 + w * 1024 + lane * 4;
  f32x4 zcur[4];
  #pragma unroll
  for (int q = 0; q < 4; ++q) zcur[q] = *(const f32x4*)(pz + q * 256);

  for (int tt = 0; tt < L; ++tt) {
    const int t  = t0 + tt;
    const int pb = (t - 1) & 1, cb = t & 1;
    // seq write of h_{t-1}: one coalesced 8B store (off critical path)
    if (tt > 0)
      *(ull*)(seqrow + (size_t)(t - 1) * U_) =
          *(const ull*)&h_stage[pb][s_kt][s_l][s_p0];

    // kt=0 consumes zcur as MFMA C-in directly
    f32x4 acc[4];
    {
      short8 a = *(const short8*)&h_stage[pb][0][lane][0];
      acc[0] = __builtin_amdgcn_mfma_f32_16x16x32_bf16(a, wf[0][0], zcur[0], 0, 0, 0);
      acc[1] = __builtin_amdgcn_mfma_f32_16x16x32_bf16(a, wf[1][0], zcur[1], 0, 0, 0);
      acc[2] = __builtin_amdgcn_mfma_f32_16x16x32_bf16(a, wf[2][0], zcur[2], 0, 0, 0);
      acc[3] = __builtin_amdgcn_mfma_f32_16x16x32_bf16(a, wf[3][0], zcur[3], 0, 0, 0);
    }
    // prefetch xz for t+1 (full-step lead >= HBM/L3 latency)
    {
      const int ntt = (tt + 1 < L) ? tt + 1 : tt;
      const float* pn = pz + (size_t)ntt * 16384;
      #pragma unroll
      for (int q = 0; q < 4; ++q) zcur[q] = *(const f32x4*)(pn + q * 256);
    }
    #pragma unroll
    for (int kt = 1; kt < 8; ++kt) {
      short8 a = *(const short8*)&h_stage[pb][kt][lane][0];
      acc[0] = __builtin_amdgcn_mfma_f32_16x16x32_bf16(a, wf[0][kt], acc[0], 0, 0, 0);
      acc[1] = __builtin_amdgcn_mfma_f32_16x16x32_bf16(a, wf[1][kt], acc[1], 0, 0, 0);
      acc[2] = __builtin_amdgcn_mfma_f32_16x16x32_bf16(a, wf[2][kt], acc[2], 0, 0, 0);
      acc[3] = __builtin_amdgcn_mfma_f32_16x16x32_bf16(a, wf[3][kt], acc[3], 0, 0, 0);
    }
    // gates fully in registers (thread owns unit u, rows rg*4+j)
    #pragma unroll
    for (int j = 0; j < 4; ++j) {
      const float zi = acc[0][j], zf = acc[1][j];
      const float zg = acc[2][j], zo = acc[3][j];
      const float ii = sigm(zi), ff = sigm(zf);
      const float gg = zg * sigm(zg), oo = sigm(zo);
      const float cc = ff * cst[j] + ii * gg;
      cst[j] = cc;
      h_stage[cb][kta][ga + rg * 4 + j][posa] = f2bf(oo * (cc * sigm(cc)));
    }
    BARRIER_LDS();   // h_t visible; also separates pb reads from next write
  }
  // epilogue: last h -> seq, cst checkpoint (f32 exact)
  *(ull*)(seqrow + (size_t)(t0 + L - 1) * U_) =
      *(const ull*)&h_stage[(t0 + L - 1) & 1][s_kt][s_l][s_p0];
  #pragma unroll
  for (int j = 0; j < 4; ++j)
    cstbuf[(size_t)(bg * 16 + rg * 4 + j) * U_ + u] = cst[j];
}

// ---------------------------------------------------------------------------
// Fallback (ws too small): R8's verified pairwise kernel.
// ---------------------------------------------------------------------------
__global__ __launch_bounds__(512, 2) void lstm_fallback(
    const float* __restrict__ x, const float* __restrict__ kern,
    const float* __restrict__ rker, const float* __restrict__ bias,
    uint16_t* __restrict__ seq, ull* __restrict__ hbuf)
{
  const int tid  = threadIdx.x;
  const int lane = tid & 63;
  const int wv   = tid >> 6;
  const int il   = lane & 15;
  const int rg   = lane >> 4;
  const int bg   = blockIdx.x & 15;
  const int m    = blockIdx.x >> 4;

  __shared__ __align__(16) uint16_t x_stage[4][64][8];
  __shared__ __align__(16) uint16_t h_stage[2][8][64][8];
  __shared__ __align__(16) uint16_t kern_lds[8192 * 8];

  short8 wf[4][8];
  float  bias_r[4];
  #pragma unroll
  for (int q = 0; q < 4; ++q) {
    const int gcol = q * U_ + m * 128 + wv * 16 + il;
    bias_r[q] = bias[gcol];
    #pragma unroll
    for (int kk = 0; kk < 8; ++kk) {
      const int ktg = ((kk & 4) ? (m ^ 1) : m) * 4 + (kk & 3);
      short8 v;
      #pragma unroll
      for (int j = 0; j < 8; ++j)
        v[j] = (short)f2bf(rker[(size_t)(ktg * 32 + rg * 8 + j) * G4U + gcol]);
      wf[q][kk] = v;
    }
  }
  for (int s = 0; s < 16; ++s) {
    const int slot = tid + s * 512;
    const int ln = slot & 63, kt = (slot >> 6) & 3, ct = slot >> 8;
    const int col = (ct >> 3) * U_ + m * 128 + (ct & 7) * 16 + (ln & 15);
    const int kb  = kt * 32 + (ln >> 4) * 8;
    short8 v;
    #pragma unroll
    for (int j = 0; j < 8; ++j)
      v[j] = (short)f2bf(kern[(size_t)(kb + j) * G4U + col]);
    *(short8*)&kern_lds[(size_t)slot * 8] = v;
  }
  const int xkt = tid >> 7;
  const int xln = (tid >> 1) & 63;
  const int xj0 = (tid & 1) * 4;
  const int xrow = xln & 15;
  const int xk0  = xkt * 32 + (xln >> 4) * 8 + xj0;
  const int Ua  = m * 128 + wv * 16 + il;
  const int kta = Ua >> 5, ga = ((Ua & 31) >> 3) * 16, posa = Ua & 7;
  ull* const pub_s = hbuf + (size_t)(bg * 2 + m) * 2048;
  const ull* const pub_p = hbuf + (size_t)(bg * 2 + (m ^ 1)) * 2048;
  float cst[4];
  #pragma unroll
  for (int j = 0; j < 4; ++j) cst[j] = 0.f;
  float xp[4];
  {
    const float* p = x + ((size_t)(bg * 16 + xrow) * T_ + 0) * F_ + xk0;
    #pragma unroll
    for (int j = 0; j < 4; ++j) xp[j] = p[j];
    uint16_t* d = (uint16_t*)x_stage + tid * 4;
    #pragma unroll
    for (int j = 0; j < 4; ++j) d[j] = f2bf(xp[j]);
  }
  __syncthreads();
  for (int t = 0; t < T_; ++t) {
    const ull* pp = pub_p + (size_t)((t - 1) & 1) * 1024 + tid * 2;
    ull pv0 = 0, pv1 = 0;
    if (t > 0) {
      pv0 = ald(pp); pv1 = ald(pp + 1);
      __builtin_amdgcn_sched_barrier(0);
    }
    {
      const int tn = (t + 1 < T_) ? t + 1 : t;
      const float* p = x + ((size_t)(bg * 16 + xrow) * T_ + tn) * F_ + xk0;
      #pragma unroll
      for (int j = 0; j < 4; ++j) xp[j] = p[j];
    }
    f32x4 acc[4];
    #pragma unroll
    for (int q = 0; q < 4; ++q)
      acc[q] = (f32x4){bias_r[q], bias_r[q], bias_r[q], bias_r[q]};
    #pragma unroll
    for (int kt = 0; kt < 4; ++kt) {
      short8 a = *(const short8*)&x_stage[kt][lane][0];
      #pragma unroll
      for (int q = 0; q < 4; ++q) {
        short8 b = *(const short8*)&kern_lds[(size_t)(((q * 8 + wv) * 4 + kt) * 64 + lane) * 8];
        acc[q] = __builtin_amdgcn_mfma_f32_16x16x32_bf16(a, b, acc[q], 0, 0, 0);
      }
    }
    if (t > 0) {
      const int p_ = (t - 1) & 1;
      #pragma unroll
      for (int kk = 0; kk < 4; ++kk) {
        short8 a = *(const short8*)&h_stage[p_][m * 4 + kk][lane][0];
        #pragma unroll
        for (int q = 0; q < 4; ++q)
          acc[q] = __builtin_amdgcn_mfma_f32_16x16x32_bf16(a, wf[q][kk], acc[q], 0, 0, 0);
      }
      const uint32_t expt = (uint32_t)t;
      while (((uint32_t)(pv0 >> 32) != expt) | ((uint32_t)(pv1 >> 32) != expt)) {
        pv0 = ald(pp); pv1 = ald(pp + 1);
      }
      const int u_loc = tid >> 2;
      const int U  = (m ^ 1) * 128 + u_loc;
      const int kt = U >> 5, g = ((U & 31) >> 3) * 16, pos = U & 7;
      const int rb = (tid & 3) * 4;
      h_stage[p_][kt][g + rb + 0][pos] = (uint16_t)pv0;
      h_stage[p_][kt][g + rb + 1][pos] = (uint16_t)(pv0 >> 16);
      h_stage[p_][kt][g + rb + 2][pos] = (uint16_t)pv1;
      h_stage[p_][kt][g + rb + 3][pos] = (uint16_t)(pv1 >> 16);
    }
    BARRIER_LDS();
    if (t > 0) {
      const int p_ = (t - 1) & 1;
      #pragma unroll
      for (int kk = 0; kk < 4; ++kk) {
        short8 a = *(const short8*)&h_stage[p_][(m ^ 1) * 4 + kk][lane][0];
        #pragma unroll
        for (int q = 0; q < 4; ++q)
          acc[q] = __builtin_amdgcn_mfma_f32_16x16x32_bf16(a, wf[q][4 + kk], acc[q], 0, 0, 0);
      }
    }
    {
      uint16_t* d = (uint16_t*)x_stage + tid * 4;
      #pragma unroll
      for (int j = 0; j < 4; ++j) d[j] = f2bf(xp[j]);
    }
    {
      uint16_t b16[4];
      #pragma unroll
      for (int j = 0; j < 4; ++j) {
        const float zi = acc[0][j], zf = acc[1][j];
        const float zg = acc[2][j], zo = acc[3][j];
        const float ii = sigm(zi), ff = sigm(zf);
        const float gg = zg * sigm(zg), oo = sigm(zo);
        const float c  = ff * cst[j] + ii * gg;
        cst[j] = c;
        b16[j] = f2bf(oo * (c * sigm(c)));
      }
      const int s2 = t & 1;
      ull* pw = pub_s + (size_t)s2 * 1024 + (size_t)(wv * 16 + il) * 8 + rg * 2;
      const ull tg = (ull)(uint32_t)(t + 1) << 32;
      __hip_atomic_store(pw,     (ull)((uint32_t)b16[0] | ((uint32_t)b16[1] << 16)) | tg,
                         __ATOMIC_RELAXED, __HIP_MEMORY_SCOPE_AGENT);
      __hip_atomic_store(pw + 1, (ull)((uint32_t)b16[2] | ((uint32_t)b16[3] << 16)) | tg,
                         __ATOMIC_RELAXED, __HIP_MEMORY_SCOPE_AGENT);
      #pragma unroll
      for (int j = 0; j < 4; ++j) {
        h_stage[s2][kta][ga + rg * 4 + j][posa] = b16[j];
        seq[((size_t)(bg * 16 + rg * 4 + j) * T_ + t) * U_ + Ua] = b16[j];
      }
    }
    BARRIER_LDS();
  }
}

// ---------------------------------------------------------------------------
// Head GEMM + reduce (unchanged, verified).
// ---------------------------------------------------------------------------
__global__ __launch_bounds__(256, 1) void head_kernel(
    const uint16_t* __restrict__ seq, const float* __restrict__ w_out,
    float* __restrict__ partials)
{
  const int g    = blockIdx.x;
  const int tid  = threadIdx.x;
  const int lane = tid & 63;
  const int wv   = tid >> 6;

  f32x4 acc[4][4];
  #pragma unroll
  for (int i = 0; i < 4; ++i)
    #pragma unroll
    for (int c = 0; c < 4; ++c) acc[i][c] = (f32x4){0.f, 0.f, 0.f, 0.f};

  for (int ks = 0; ks < 64; ++ks) {
    const int krow = g * 2048 + ks * 32 + (lane >> 4) * 8;
    short8 bf[4];
    #pragma unroll
    for (int c = 0; c < 4; ++c) {
      short8 v;
      #pragma unroll
      for (int j = 0; j < 8; ++j)
        v[j] = (short)f2bf(w_out[(size_t)(krow + j) * H_ + c * 16 + (lane & 15)]);
      bf[c] = v;
    }
    #pragma unroll
    for (int i = 0; i < 4; ++i) {
      const int b = (wv * 4 + i) * 16 + (lane & 15);
      short8 a = *(const short8*)(seq + (size_t)b * (T_ * U_) + krow);
      #pragma unroll
      for (int c = 0; c < 4; ++c)
        acc[i][c] = __builtin_amdgcn_mfma_f32_16x16x32_bf16(a, bf[c], acc[i][c], 0, 0, 0);
    }
  }
  #pragma unroll
  for (int i = 0; i < 4; ++i)
    #pragma unroll
    for (int c = 0; c < 4; ++c)
      #pragma unroll
      for (int r = 0; r < 4; ++r) {
        const int b = wv * 64 + i * 16 + (lane >> 4) * 4 + r;
        partials[((size_t)g * B_ + b) * H_ + c * 16 + (lane & 15)] = acc[i][c][r];
      }
}

__global__ void reduce_kernel(const float* __restrict__ partials,
                              const float* __restrict__ b_out,
                              float* __restrict__ out)
{
  const int i = blockIdx.x * 256 + threadIdx.x;
  float s = b_out[i & (H_ - 1)];
  #pragma unroll 8
  for (int g = 0; g < 64; ++g) s += partials[(size_t)g * (B_ * H_) + i];
  out[i] = s;
}

// ---------------------------------------------------------------------------
extern "C" void kernel_launch(void* const* d_in, const int* in_sizes, int n_in,
                              void* d_out, int out_size, void* d_ws, size_t ws_size,
                              hipStream_t stream) {
  (void)in_sizes; (void)n_in; (void)out_size;
  const float* x     = (const float*)d_in[0];
  const float* kern  = (const float*)d_in[1];
  const float* rker  = (const float*)d_in[2];
  const float* bias  = (const float*)d_in[3];
  const float* w_out = (const float*)d_in[4];
  const float* b_out = (const float*)d_in[5];
  float* out = (float*)d_out;

  char* ws = (char*)d_ws;
  const size_t seq_bytes  = (size_t)B_ * T_ * U_ * 2;    // 64 MB
  const size_t hbuf_bytes = (size_t)32 * 2048 * 8;       // 512 KB (fallback tags)
  const size_t part_bytes = (size_t)64 * B_ * H_ * 4;    // 4 MB
  const size_t cst_bytes  = (size_t)B_ * U_ * 4;         // 256 KB
  uint16_t* seq      = (uint16_t*)ws;
  ull*      hbuf     = (ull*)(ws + seq_bytes);
  float*    partials = (float*)(ws + seq_bytes + hbuf_bytes);
  float*    cstbuf   = (float*)(ws + seq_bytes + hbuf_bytes + part_bytes);
  const size_t xz_off = seq_bytes + hbuf_bytes + part_bytes + cst_bytes;
  float* xzbuf = (float*)(ws + xz_off);

  // largest phase length whose f32 xz tile fits: xz(L) = B*L*4U*4 = L MB
  int L = 0;
  const int cand[4] = {128, 64, 32, 16};
  for (int i = 0; i < 4; ++i) {
    if (ws_size >= xz_off + (size_t)cand[i] * 1048576) { L = cand[i]; break; }
  }

  if (L > 0) {
    for (int t0 = 0; t0 < T_; t0 += L) {
      xz_pre<<<2 * L, 256, 0, stream>>>(x, kern, bias, xzbuf, t0, L);
      lstm_phase<<<16, 1024, 0, stream>>>(rker, seq, xzbuf, cstbuf, t0, L);
    }
  } else {
    hipMemsetAsync(hbuf, 0, hbuf_bytes, stream);   // tag re-init (graph replays)
    lstm_fallback<<<32, 512, 0, stream>>>(x, kern, rker, bias, seq, hbuf);
  }
  head_kernel<<<64, 256, 0, stream>>>(seq, w_out, partials);
  reduce_kernel<<<64, 256, 0, stream>>>(partials, b_out, out);
}

// Round 15
// 1596.409 us; speedup vs baseline: 2.4652x; 2.4652x over previous
//
#include <hip/hip_runtime.h>
#include <stdint.h>

#define B_ 256
#define T_ 512
#define F_ 128
#define U_ 256
#define H_ 64
#define G4U 1024

typedef __attribute__((ext_vector_type(8))) short short8;
typedef __attribute__((ext_vector_type(4))) float f32x4;
typedef unsigned long long ull;

// LDS-only barrier: NO vmcnt drain.
#define BARRIER_LDS() asm volatile("s_waitcnt lgkmcnt(0)\ns_barrier" ::: "memory")

__device__ __forceinline__ uint16_t f2bf(float f) {
  uint32_t u = __builtin_bit_cast(uint32_t, f);
  u += 0x7fffu + ((u >> 16) & 1u);
  return (uint16_t)(u >> 16);
}
__device__ __forceinline__ float bf2f(uint32_t v) {
  return __builtin_bit_cast(float, (v & 0xffffu) << 16);
}
__device__ __forceinline__ float frcp(float x) {
  float r;
  asm volatile("v_rcp_f32 %0, %1" : "=v"(r) : "v"(x));
  return r;
}
__device__ __forceinline__ float sigm(float z) {   // v_exp + v_rcp fast path
  return frcp(1.0f + __expf(-z));
}
__device__ __forceinline__ ull ald(const ull* p) {
  return __hip_atomic_load(p, __ATOMIC_RELAXED, __HIP_MEMORY_SCOPE_AGENT);
}

// ---------------------------------------------------------------------------
// xz_pre v3: xz = bias + x_t @ kernel, stored BF16 in MFMA C-layout
// (R14 lesson: the 16-WG phase kernel's pull rate caps at ~10 B/cyc/CU x
// 16 CUs ~= 384 GB/s; f32 xz needed 348 -> WAS the wall. bf16 halves it.)
//   xz[(bg*L+tt)*16384 + (wd*4+q)*256 + lane*4 + r]  (u16 elements)
// Grid = 16bg x 2hp x (L/16)tc blocks x 256 thr (wave = gate q).
// ---------------------------------------------------------------------------
__global__ __launch_bounds__(256, 1) void xz_pre(
    const float* __restrict__ x, const float* __restrict__ kern,
    const float* __restrict__ bias, uint16_t* __restrict__ xz,
    int t0, int L)
{
  const int tid  = threadIdx.x;
  const int lane = tid & 63;
  const int q    = tid >> 6;
  const int il   = lane & 15;
  const int bx   = blockIdx.x;
  const int bg   = bx & 15;
  const int hp   = (bx >> 4) & 1;
  const int tc   = bx >> 5;

  __shared__ __align__(16) uint16_t kern_lds[8192 * 8];     // 128 KB
  __shared__ __align__(16) uint16_t x_stage[2][4][64][8];   // 8 KB dbuf

  for (int s = 0; s < 32; ++s) {
    const int slot = tid + s * 256;
    const int l = slot & 63, kt = (slot >> 6) & 3, ctl = (slot >> 8) & 7, qq = slot >> 11;
    const int col = qq * 256 + (hp * 8 + ctl) * 16 + (l & 15);
    const int kb  = kt * 32 + (l >> 4) * 8;
    short8 v;
    #pragma unroll
    for (int j = 0; j < 8; ++j)
      v[j] = (short)f2bf(kern[(size_t)(kb + j) * G4U + col]);
    *(short8*)&kern_lds[(size_t)slot * 8] = v;
  }
  float bias_r[8];
  #pragma unroll
  for (int ctl = 0; ctl < 8; ++ctl)
    bias_r[ctl] = bias[q * 256 + (hp * 8 + ctl) * 16 + il];

  const int xrow = tid & 15, xfb = (tid >> 4) * 8;
  const int xs_kt = xfb >> 5, xs_l = ((xfb >> 3) & 3) * 16 + xrow;

  float xv[8];
  {
    const float* p = x + ((size_t)(bg * 16 + xrow) * T_ + (t0 + tc * 16)) * F_ + xfb;
    #pragma unroll
    for (int j = 0; j < 8; ++j) xv[j] = p[j];
  }
  __syncthreads();

  for (int tt2 = 0; tt2 < 16; ++tt2) {
    const int t = t0 + tc * 16 + tt2;
    const int bb = tt2 & 1;
    {
      uint16_t* d = &x_stage[bb][xs_kt][xs_l][0];
      #pragma unroll
      for (int j = 0; j < 8; ++j) d[j] = f2bf(xv[j]);
    }
    BARRIER_LDS();
    {
      const int tn = (tt2 < 15) ? t + 1 : t;
      const float* p = x + ((size_t)(bg * 16 + xrow) * T_ + tn) * F_ + xfb;
      #pragma unroll
      for (int j = 0; j < 8; ++j) xv[j] = p[j];
    }
    f32x4 acc[8];
    #pragma unroll
    for (int ctl = 0; ctl < 8; ++ctl)
      acc[ctl] = (f32x4){bias_r[ctl], bias_r[ctl], bias_r[ctl], bias_r[ctl]};
    #pragma unroll
    for (int kt = 0; kt < 4; ++kt) {
      short8 a = *(const short8*)&x_stage[bb][kt][lane][0];
      #pragma unroll
      for (int ctl = 0; ctl < 8; ++ctl) {
        short8 b = *(const short8*)&kern_lds[(size_t)(((q * 8 + ctl) * 4 + kt) * 64 + lane) * 8];
        acc[ctl] = __builtin_amdgcn_mfma_f32_16x16x32_bf16(a, b, acc[ctl], 0, 0, 0);
      }
    }
    uint16_t* ob = xz + (size_t)(bg * L + (t - t0)) * 16384;
    #pragma unroll
    for (int ctl = 0; ctl < 8; ++ctl) {
      const int wd = hp * 8 + ctl;
      const uint32_t lo = (uint32_t)f2bf(acc[ctl][0]) | ((uint32_t)f2bf(acc[ctl][1]) << 16);
      const uint32_t hi = (uint32_t)f2bf(acc[ctl][2]) | ((uint32_t)f2bf(acc[ctl][3]) << 16);
      *(ull*)(ob + (size_t)(wd * 4 + q) * 256 + lane * 4) = (ull)lo | ((ull)hi << 32);
    }
  }
}

// ---------------------------------------------------------------------------
// lstm_phase v4: EXACT R12 structure (512 thr, (512,2), wfv[3][2][8] in regs
// + rec3 in LDS, 2-pass, 1 barrier/step -- the PROVEN-resident codegen shape;
// R13/14's 1024-thr blocks demote weights regardless of launch_bounds) with
// ONE change: xz loads are bf16 (4 x ull per pass) + shift-unpack into acc.
// Halves the xz pull to ~174 GB/s, under the 16-CU ~384 GB/s ceiling.
// ---------------------------------------------------------------------------
__global__ __launch_bounds__(512, 2) void lstm_phase(
    const float* __restrict__ rker, uint16_t* __restrict__ seq,
    const uint16_t* __restrict__ xz, float* __restrict__ cstbuf,
    int t0, int L)
{
  const int tid  = threadIdx.x;
  const int lane = tid & 63;
  const int w    = tid >> 6;
  const int il   = lane & 15;
  const int rg   = lane >> 4;
  const int bg   = blockIdx.x;

  __shared__ __align__(16) uint16_t h_stage[2][8][64][8];       // 16 KB dbuf
  __shared__ __align__(16) uint16_t rec3[16][8][64][8];         // 128 KB (q=3)

  // rec q=0..2 B-frags in registers (all indices static -- rule #20)
  short8 wfv[3][2][8];
  #pragma unroll
  for (int q = 0; q < 3; ++q)
    #pragma unroll
    for (int d = 0; d < 2; ++d) {
      const int col = q * 256 + (w * 2 + d) * 16 + il;
      #pragma unroll
      for (int kt = 0; kt < 8; ++kt) {
        short8 v;
        #pragma unroll
        for (int j = 0; j < 8; ++j)
          v[j] = (short)f2bf(rker[(size_t)(kt * 32 + rg * 8 + j) * G4U + col]);
        wfv[q][d][kt] = v;
      }
    }
  // rec q=3 -> LDS
  for (int s = 0; s < 16; ++s) {
    const int slot = tid + s * 512;
    const int l = slot & 63, kt = (slot >> 6) & 7, wd = slot >> 9;
    const int col = 768 + wd * 16 + (l & 15);
    const int kb  = kt * 32 + (l >> 4) * 8;
    short8 v;
    #pragma unroll
    for (int j = 0; j < 8; ++j)
      v[j] = (short)f2bf(rker[(size_t)(kb + j) * G4U + col]);
    *(short8*)&rec3[wd][kt][l][0] = v;
  }

  // flat-copy constants (seq <-> h_stage): thread owns 16B = 8 units x 1 row
  const int cl  = tid & 63, ckt = tid >> 6;
  const int crow = cl & 15, cub = ckt * 32 + ((cl >> 4) & 3) * 8;
  uint16_t* const seqrow = seq + (size_t)(bg * 16 + crow) * T_ * U_ + cub;

  float cst[2][4];
  if (t0 == 0) {
    #pragma unroll
    for (int d = 0; d < 2; ++d)
      #pragma unroll
      for (int j = 0; j < 4; ++j) cst[d][j] = 0.f;
    ((ull*)&h_stage[1][0][0][0])[tid * 2]     = 0;   // zero buf[1] (=h_{-1})
    ((ull*)&h_stage[1][0][0][0])[tid * 2 + 1] = 0;
  } else {
    #pragma unroll
    for (int d = 0; d < 2; ++d)
      #pragma unroll
      for (int j = 0; j < 4; ++j)
        cst[d][j] = cstbuf[(size_t)(bg * 16 + rg * 4 + j) * U_ + w * 32 + d * 16 + il];
    *(short8*)&h_stage[1][ckt][cl][0] =
        *(const short8*)(seqrow + (size_t)(t0 - 1) * U_);
  }
  __syncthreads();

  // per-lane xz pointer in u16 units (pass: d0->d1 = +1024, next-t = +16384)
  const uint16_t* const pz = xz + (size_t)bg * L * 16384 + (w * 2) * 1024 + lane * 4;
  ull zc[4];
  #pragma unroll
  for (int q = 0; q < 4; ++q) zc[q] = *(const ull*)(pz + q * 256);

  for (int tt = 0; tt < L; ++tt) {
    const int t  = t0 + tt;
    const int pb = (t - 1) & 1, cb = t & 1;
    // seq write of h_{t-1}: ONE coalesced 16B store (off critical path)
    if (tt > 0)
      *(short8*)(seqrow + (size_t)(t - 1) * U_) =
          *(const short8*)&h_stage[pb][ckt][cl][0];

    uint16_t hb[2][4];
    #pragma unroll
    for (int d = 0; d < 2; ++d) {
      // acc <- bf16 unpack of zc (independent ops, pipeline well)
      f32x4 acc[4];
      #pragma unroll
      for (int q = 0; q < 4; ++q) {
        const uint32_t lo = (uint32_t)zc[q];
        const uint32_t hi = (uint32_t)(zc[q] >> 32);
        acc[q][0] = bf2f(lo); acc[q][1] = bf2f(lo >> 16);
        acc[q][2] = bf2f(hi); acc[q][3] = bf2f(hi >> 16);
      }
      // prefetch NEXT pass (SSA: new values, loads issue early)
      {
        const int ntt = (d == 0) ? tt : ((tt + 1 < L) ? tt + 1 : tt);
        const int nd  = d ^ 1;
        const uint16_t* pn = pz + (size_t)ntt * 16384 + nd * 1024;
        #pragma unroll
        for (int q = 0; q < 4; ++q) zc[q] = *(const ull*)(pn + q * 256);
      }
      #pragma unroll
      for (int kt = 0; kt < 8; ++kt) {
        short8 a = *(const short8*)&h_stage[pb][kt][lane][0];
        acc[0] = __builtin_amdgcn_mfma_f32_16x16x32_bf16(a, wfv[0][d][kt], acc[0], 0, 0, 0);
        acc[1] = __builtin_amdgcn_mfma_f32_16x16x32_bf16(a, wfv[1][d][kt], acc[1], 0, 0, 0);
        acc[2] = __builtin_amdgcn_mfma_f32_16x16x32_bf16(a, wfv[2][d][kt], acc[2], 0, 0, 0);
        short8 b3 = *(const short8*)&rec3[w * 2 + d][kt][lane][0];
        acc[3] = __builtin_amdgcn_mfma_f32_16x16x32_bf16(a, b3, acc[3], 0, 0, 0);
      }
      // gates: v_exp + v_rcp fast path
      #pragma unroll
      for (int j = 0; j < 4; ++j) {
        const float zi = acc[0][j], zf = acc[1][j];
        const float zg = acc[2][j], zo = acc[3][j];
        const float ii = sigm(zi), ff = sigm(zf);
        const float gg = zg * sigm(zg), oo = sigm(zo);
        const float cc = ff * cst[d][j] + ii * gg;
        cst[d][j] = cc;
        hb[d][j] = f2bf(oo * (cc * sigm(cc)));
      }
    }
    // write h_t -> buf[cb] (dbuf => single barrier per step)
    #pragma unroll
    for (int d = 0; d < 2; ++d)
      #pragma unroll
      for (int j = 0; j < 4; ++j)
        h_stage[cb][w][(d * 2 + (il >> 3)) * 16 + rg * 4 + j][il & 7] = hb[d][j];
    BARRIER_LDS();
  }
  // epilogue: last h -> seq, cst checkpoint (f32 exact)
  *(short8*)(seqrow + (size_t)(t0 + L - 1) * U_) =
      *(const short8*)&h_stage[(t0 + L - 1) & 1][ckt][cl][0];
  #pragma unroll
  for (int d = 0; d < 2; ++d)
    #pragma unroll
    for (int j = 0; j < 4; ++j)
      cstbuf[(size_t)(bg * 16 + rg * 4 + j) * U_ + w * 32 + d * 16 + il] = cst[d][j];
}

// ---------------------------------------------------------------------------
// Fallback (ws too small): R8's verified pairwise kernel.
// ---------------------------------------------------------------------------
__global__ __launch_bounds__(512, 2) void lstm_fallback(
    const float* __restrict__ x, const float* __restrict__ kern,
    const float* __restrict__ rker, const float* __restrict__ bias,
    uint16_t* __restrict__ seq, ull* __restrict__ hbuf)
{
  const int tid  = threadIdx.x;
  const int lane = tid & 63;
  const int wv   = tid >> 6;
  const int il   = lane & 15;
  const int rg   = lane >> 4;
  const int bg   = blockIdx.x & 15;
  const int m    = blockIdx.x >> 4;

  __shared__ __align__(16) uint16_t x_stage[4][64][8];
  __shared__ __align__(16) uint16_t h_stage[2][8][64][8];
  __shared__ __align__(16) uint16_t kern_lds[8192 * 8];

  short8 wf[4][8];
  float  bias_r[4];
  #pragma unroll
  for (int q = 0; q < 4; ++q) {
    const int gcol = q * U_ + m * 128 + wv * 16 + il;
    bias_r[q] = bias[gcol];
    #pragma unroll
    for (int kk = 0; kk < 8; ++kk) {
      const int ktg = ((kk & 4) ? (m ^ 1) : m) * 4 + (kk & 3);
      short8 v;
      #pragma unroll
      for (int j = 0; j < 8; ++j)
        v[j] = (short)f2bf(rker[(size_t)(ktg * 32 + rg * 8 + j) * G4U + gcol]);
      wf[q][kk] = v;
    }
  }
  for (int s = 0; s < 16; ++s) {
    const int slot = tid + s * 512;
    const int ln = slot & 63, kt = (slot >> 6) & 3, ct = slot >> 8;
    const int col = (ct >> 3) * U_ + m * 128 + (ct & 7) * 16 + (ln & 15);
    const int kb  = kt * 32 + (ln >> 4) * 8;
    short8 v;
    #pragma unroll
    for (int j = 0; j < 8; ++j)
      v[j] = (short)f2bf(kern[(size_t)(kb + j) * G4U + col]);
    *(short8*)&kern_lds[(size_t)slot * 8] = v;
  }
  const int xkt = tid >> 7;
  const int xln = (tid >> 1) & 63;
  const int xj0 = (tid & 1) * 4;
  const int xrow = xln & 15;
  const int xk0  = xkt * 32 + (xln >> 4) * 8 + xj0;
  const int Ua  = m * 128 + wv * 16 + il;
  const int kta = Ua >> 5, ga = ((Ua & 31) >> 3) * 16, posa = Ua & 7;
  ull* const pub_s = hbuf + (size_t)(bg * 2 + m) * 2048;
  const ull* const pub_p = hbuf + (size_t)(bg * 2 + (m ^ 1)) * 2048;
  float cst[4];
  #pragma unroll
  for (int j = 0; j < 4; ++j) cst[j] = 0.f;
  float xp[4];
  {
    const float* p = x + ((size_t)(bg * 16 + xrow) * T_ + 0) * F_ + xk0;
    #pragma unroll
    for (int j = 0; j < 4; ++j) xp[j] = p[j];
    uint16_t* d = (uint16_t*)x_stage + tid * 4;
    #pragma unroll
    for (int j = 0; j < 4; ++j) d[j] = f2bf(xp[j]);
  }
  __syncthreads();
  for (int t = 0; t < T_; ++t) {
    const ull* pp = pub_p + (size_t)((t - 1) & 1) * 1024 + tid * 2;
    ull pv0 = 0, pv1 = 0;
    if (t > 0) {
      pv0 = ald(pp); pv1 = ald(pp + 1);
      __builtin_amdgcn_sched_barrier(0);
    }
    {
      const int tn = (t + 1 < T_) ? t + 1 : t;
      const float* p = x + ((size_t)(bg * 16 + xrow) * T_ + tn) * F_ + xk0;
      #pragma unroll
      for (int j = 0; j < 4; ++j) xp[j] = p[j];
    }
    f32x4 acc[4];
    #pragma unroll
    for (int q = 0; q < 4; ++q)
      acc[q] = (f32x4){bias_r[q], bias_r[q], bias_r[q], bias_r[q]};
    #pragma unroll
    for (int kt = 0; kt < 4; ++kt) {
      short8 a = *(const short8*)&x_stage[kt][lane][0];
      #pragma unroll
      for (int q = 0; q < 4; ++q) {
        short8 b = *(const short8*)&kern_lds[(size_t)(((q * 8 + wv) * 4 + kt) * 64 + lane) * 8];
        acc[q] = __builtin_amdgcn_mfma_f32_16x16x32_bf16(a, b, acc[q], 0, 0, 0);
      }
    }
    if (t > 0) {
      const int p_ = (t - 1) & 1;
      #pragma unroll
      for (int kk = 0; kk < 4; ++kk) {
        short8 a = *(const short8*)&h_stage[p_][m * 4 + kk][lane][0];
        #pragma unroll
        for (int q = 0; q < 4; ++q)
          acc[q] = __builtin_amdgcn_mfma_f32_16x16x32_bf16(a, wf[q][kk], acc[q], 0, 0, 0);
      }
      const uint32_t expt = (uint32_t)t;
      while (((uint32_t)(pv0 >> 32) != expt) | ((uint32_t)(pv1 >> 32) != expt)) {
        pv0 = ald(pp); pv1 = ald(pp + 1);
      }
      const int u_loc = tid >> 2;
      const int U  = (m ^ 1) * 128 + u_loc;
      const int kt = U >> 5, g = ((U & 31) >> 3) * 16, pos = U & 7;
      const int rb = (tid & 3) * 4;
      h_stage[p_][kt][g + rb + 0][pos] = (uint16_t)pv0;
      h_stage[p_][kt][g + rb + 1][pos] = (uint16_t)(pv0 >> 16);
      h_stage[p_][kt][g + rb + 2][pos] = (uint16_t)pv1;
      h_stage[p_][kt][g + rb + 3][pos] = (uint16_t)(pv1 >> 16);
    }
    BARRIER_LDS();
    if (t > 0) {
      const int p_ = (t - 1) & 1;
      #pragma unroll
      for (int kk = 0; kk < 4; ++kk) {
        short8 a = *(const short8*)&h_stage[p_][(m ^ 1) * 4 + kk][lane][0];
        #pragma unroll
        for (int q = 0; q < 4; ++q)
          acc[q] = __builtin_amdgcn_mfma_f32_16x16x32_bf16(a, wf[q][4 + kk], acc[q], 0, 0, 0);
      }
    }
    {
      uint16_t* d = (uint16_t*)x_stage + tid * 4;
      #pragma unroll
      for (int j = 0; j < 4; ++j) d[j] = f2bf(xp[j]);
    }
    {
      uint16_t b16[4];
      #pragma unroll
      for (int j = 0; j < 4; ++j) {
        const float zi = acc[0][j], zf = acc[1][j];
        const float zg = acc[2][j], zo = acc[3][j];
        const float ii = sigm(zi), ff = sigm(zf);
        const float gg = zg * sigm(zg), oo = sigm(zo);
        const float c  = ff * cst[j] + ii * gg;
        cst[j] = c;
        b16[j] = f2bf(oo * (c * sigm(c)));
      }
      const int s2 = t & 1;
      ull* pw = pub_s + (size_t)s2 * 1024 + (size_t)(wv * 16 + il) * 8 + rg * 2;
      const ull tg = (ull)(uint32_t)(t + 1) << 32;
      __hip_atomic_store(pw,     (ull)((uint32_t)b16[0] | ((uint32_t)b16[1] << 16)) | tg,
                         __ATOMIC_RELAXED, __HIP_MEMORY_SCOPE_AGENT);
      __hip_atomic_store(pw + 1, (ull)((uint32_t)b16[2] | ((uint32_t)b16[3] << 16)) | tg,
                         __ATOMIC_RELAXED, __HIP_MEMORY_SCOPE_AGENT);
      #pragma unroll
      for (int j = 0; j < 4; ++j) {
        h_stage[s2][kta][ga + rg * 4 + j][posa] = b16[j];
        seq[((size_t)(bg * 16 + rg * 4 + j) * T_ + t) * U_ + Ua] = b16[j];
      }
    }
    BARRIER_LDS();
  }
}

// ---------------------------------------------------------------------------
// Head GEMM + reduce (unchanged, verified).
// ---------------------------------------------------------------------------
__global__ __launch_bounds__(256, 1) void head_kernel(
    const uint16_t* __restrict__ seq, const float* __restrict__ w_out,
    float* __restrict__ partials)
{
  const int g    = blockIdx.x;
  const int tid  = threadIdx.x;
  const int lane = tid & 63;
  const int wv   = tid >> 6;

  f32x4 acc[4][4];
  #pragma unroll
  for (int i = 0; i < 4; ++i)
    #pragma unroll
    for (int c = 0; c < 4; ++c) acc[i][c] = (f32x4){0.f, 0.f, 0.f, 0.f};

  for (int ks = 0; ks < 64; ++ks) {
    const int krow = g * 2048 + ks * 32 + (lane >> 4) * 8;
    short8 bf[4];
    #pragma unroll
    for (int c = 0; c < 4; ++c) {
      short8 v;
      #pragma unroll
      for (int j = 0; j < 8; ++j)
        v[j] = (short)f2bf(w_out[(size_t)(krow + j) * H_ + c * 16 + (lane & 15)]);
      bf[c] = v;
    }
    #pragma unroll
    for (int i = 0; i < 4; ++i) {
      const int b = (wv * 4 + i) * 16 + (lane & 15);
      short8 a = *(const short8*)(seq + (size_t)b * (T_ * U_) + krow);
      #pragma unroll
      for (int c = 0; c < 4; ++c)
        acc[i][c] = __builtin_amdgcn_mfma_f32_16x16x32_bf16(a, bf[c], acc[i][c], 0, 0, 0);
    }
  }
  #pragma unroll
  for (int i = 0; i < 4; ++i)
    #pragma unroll
    for (int c = 0; c < 4; ++c)
      #pragma unroll
      for (int r = 0; r < 4; ++r) {
        const int b = wv * 64 + i * 16 + (lane >> 4) * 4 + r;
        partials[((size_t)g * B_ + b) * H_ + c * 16 + (lane & 15)] = acc[i][c][r];
      }
}

__global__ void reduce_kernel(const float* __restrict__ partials,
                              const float* __restrict__ b_out,
                              float* __restrict__ out)
{
  const int i = blockIdx.x * 256 + threadIdx.x;
  float s = b_out[i & (H_ - 1)];
  #pragma unroll 8
  for (int g = 0; g < 64; ++g) s += partials[(size_t)g * (B_ * H_) + i];
  out[i] = s;
}

// ---------------------------------------------------------------------------
extern "C" void kernel_launch(void* const* d_in, const int* in_sizes, int n_in,
                              void* d_out, int out_size, void* d_ws, size_t ws_size,
                              hipStream_t stream) {
  (void)in_sizes; (void)n_in; (void)out_size;
  const float* x     = (const float*)d_in[0];
  const float* kern  = (const float*)d_in[1];
  const float* rker  = (const float*)d_in[2];
  const float* bias  = (const float*)d_in[3];
  const float* w_out = (const float*)d_in[4];
  const float* b_out = (const float*)d_in[5];
  float* out = (float*)d_out;

  char* ws = (char*)d_ws;
  const size_t seq_bytes  = (size_t)B_ * T_ * U_ * 2;    // 64 MB
  const size_t hbuf_bytes = (size_t)32 * 2048 * 8;       // 512 KB (fallback tags)
  const size_t part_bytes = (size_t)64 * B_ * H_ * 4;    // 4 MB
  const size_t cst_bytes  = (size_t)B_ * U_ * 4;         // 256 KB
  uint16_t* seq      = (uint16_t*)ws;
  ull*      hbuf     = (ull*)(ws + seq_bytes);
  float*    partials = (float*)(ws + seq_bytes + hbuf_bytes);
  float*    cstbuf   = (float*)(ws + seq_bytes + hbuf_bytes + part_bytes);
  const size_t xz_off = seq_bytes + hbuf_bytes + part_bytes + cst_bytes;
  uint16_t* xzbuf = (uint16_t*)(ws + xz_off);

  // largest phase length whose bf16 xz tile fits: xz(L) = B*L*4U*2 = L/2 MB
  int L = 0;
  const int cand[4] = {128, 64, 32, 16};
  for (int i = 0; i < 4; ++i) {
    if (ws_size >= xz_off + (size_t)cand[i] * 524288) { L = cand[i]; break; }
  }

  if (L > 0) {
    for (int t0 = 0; t0 < T_; t0 += L) {
      xz_pre<<<2 * L, 256, 0, stream>>>(x, kern, bias, xzbuf, t0, L);
      lstm_phase<<<16, 512, 0, stream>>>(rker, seq, xzbuf, cstbuf, t0, L);
    }
  } else {
    hipMemsetAsync(hbuf, 0, hbuf_bytes, stream);   // tag re-init (graph replays)
    lstm_fallback<<<32, 512, 0, stream>>>(x, kern, rker, bias, seq, hbuf);
  }
  head_kernel<<<64, 256, 0, stream>>>(seq, w_out, partials);
  reduce_kernel<<<64, 256, 0, stream>>>(partials, b_out, out);
}

// Round 16
// 1193.045 us; speedup vs baseline: 3.2987x; 1.3381x over previous
//
#include <hip/hip_runtime.h>
#include <stdint.h>

#define B_ 256
#define T_ 512
#define F_ 128
#define U_ 256
#define H_ 64
#define G4U 1024

typedef __attribute__((ext_vector_type(8))) short short8;
typedef __attribute__((ext_vector_type(4))) float f32x4;
typedef unsigned long long ull;

// LDS-only barrier: NO vmcnt drain.
#define BARRIER_LDS() asm volatile("s_waitcnt lgkmcnt(0)\ns_barrier" ::: "memory")

__device__ __forceinline__ uint16_t f2bf(float f) {
  uint32_t u = __builtin_bit_cast(uint32_t, f);
  u += 0x7fffu + ((u >> 16) & 1u);
  return (uint16_t)(u >> 16);
}
__device__ __forceinline__ float bf2f(uint32_t v) {
  return __builtin_bit_cast(float, (v & 0xffffu) << 16);
}
__device__ __forceinline__ float frcp(float x) {
  float r;
  asm volatile("v_rcp_f32 %0, %1" : "=v"(r) : "v"(x));
  return r;
}
__device__ __forceinline__ float sigm(float z) {
  return frcp(1.0f + __expf(-z));
}
__device__ __forceinline__ ull ald(const ull* p) {
  return __hip_atomic_load(p, __ATOMIC_RELAXED, __HIP_MEMORY_SCOPE_AGENT);
}

// ---------------------------------------------------------------------------
// xz_pre (R15 verbatim, proven): xz = bias + x_t@kernel, bf16, MFMA C-layout:
//   xz[(bg*L+tt)*16384 + (wd*4+q)*256 + lane*4 + r], wd = member*8 + wave.
// ---------------------------------------------------------------------------
__global__ __launch_bounds__(256, 1) void xz_pre(
    const float* __restrict__ x, const float* __restrict__ kern,
    const float* __restrict__ bias, uint16_t* __restrict__ xz,
    int t0, int L)
{
  const int tid  = threadIdx.x;
  const int lane = tid & 63;
  const int q    = tid >> 6;
  const int il   = lane & 15;
  const int bx   = blockIdx.x;
  const int bg   = bx & 15;
  const int hp   = (bx >> 4) & 1;
  const int tc   = bx >> 5;

  __shared__ __align__(16) uint16_t kern_lds[8192 * 8];     // 128 KB
  __shared__ __align__(16) uint16_t x_stage[2][4][64][8];   // 8 KB dbuf

  for (int s = 0; s < 32; ++s) {
    const int slot = tid + s * 256;
    const int l = slot & 63, kt = (slot >> 6) & 3, ctl = (slot >> 8) & 7, qq = slot >> 11;
    const int col = qq * 256 + (hp * 8 + ctl) * 16 + (l & 15);
    const int kb  = kt * 32 + (l >> 4) * 8;
    short8 v;
    #pragma unroll
    for (int j = 0; j < 8; ++j)
      v[j] = (short)f2bf(kern[(size_t)(kb + j) * G4U + col]);
    *(short8*)&kern_lds[(size_t)slot * 8] = v;
  }
  float bias_r[8];
  #pragma unroll
  for (int ctl = 0; ctl < 8; ++ctl)
    bias_r[ctl] = bias[q * 256 + (hp * 8 + ctl) * 16 + il];

  const int xrow = tid & 15, xfb = (tid >> 4) * 8;
  const int xs_kt = xfb >> 5, xs_l = ((xfb >> 3) & 3) * 16 + xrow;

  float xv[8];
  {
    const float* p = x + ((size_t)(bg * 16 + xrow) * T_ + (t0 + tc * 16)) * F_ + xfb;
    #pragma unroll
    for (int j = 0; j < 8; ++j) xv[j] = p[j];
  }
  __syncthreads();

  for (int tt2 = 0; tt2 < 16; ++tt2) {
    const int t = t0 + tc * 16 + tt2;
    const int bb = tt2 & 1;
    {
      uint16_t* d = &x_stage[bb][xs_kt][xs_l][0];
      #pragma unroll
      for (int j = 0; j < 8; ++j) d[j] = f2bf(xv[j]);
    }
    BARRIER_LDS();
    {
      const int tn = (tt2 < 15) ? t + 1 : t;
      const float* p = x + ((size_t)(bg * 16 + xrow) * T_ + tn) * F_ + xfb;
      #pragma unroll
      for (int j = 0; j < 8; ++j) xv[j] = p[j];
    }
    f32x4 acc[8];
    #pragma unroll
    for (int ctl = 0; ctl < 8; ++ctl)
      acc[ctl] = (f32x4){bias_r[ctl], bias_r[ctl], bias_r[ctl], bias_r[ctl]};
    #pragma unroll
    for (int kt = 0; kt < 4; ++kt) {
      short8 a = *(const short8*)&x_stage[bb][kt][lane][0];
      #pragma unroll
      for (int ctl = 0; ctl < 8; ++ctl) {
        short8 b = *(const short8*)&kern_lds[(size_t)(((q * 8 + ctl) * 4 + kt) * 64 + lane) * 8];
        acc[ctl] = __builtin_amdgcn_mfma_f32_16x16x32_bf16(a, b, acc[ctl], 0, 0, 0);
      }
    }
    uint16_t* ob = xz + (size_t)(bg * L + (t - t0)) * 16384;
    #pragma unroll
    for (int ctl = 0; ctl < 8; ++ctl) {
      const int wd = hp * 8 + ctl;
      const uint32_t lo = (uint32_t)f2bf(acc[ctl][0]) | ((uint32_t)f2bf(acc[ctl][1]) << 16);
      const uint32_t hi = (uint32_t)f2bf(acc[ctl][2]) | ((uint32_t)f2bf(acc[ctl][3]) << 16);
      *(ull*)(ob + (size_t)(wd * 4 + q) * 256 + lane * 4) = (ull)lo | ((ull)hi << 32);
    }
  }
}

// ---------------------------------------------------------------------------
// lstm_pair: R8's PROVEN pairwise tagged-sync kernel with the x-projection
// phase replaced by precomputed xz (R15 null showed xz-BW/unpack are free;
// R8's x-phase was ~2000 cyc/step of per-CU LDS work -- deleted here, along
// with kern_lds). 32 WGs x 512 thr, (512,2) proven-resident shape.
// Phase-tiled over t (xz tile = L/2 MB): h carries through hbuf (absolute
// tags survive phase boundaries; own half restored from own publishes),
// cst via cstbuf (f32 exact). Sync protocol byte-for-byte R8.
// ---------------------------------------------------------------------------
__global__ __launch_bounds__(512, 2) void lstm_pair(
    const float* __restrict__ rker, uint16_t* __restrict__ seq,
    ull* __restrict__ hbuf, const uint16_t* __restrict__ xz,
    float* __restrict__ cstbuf, int t0, int L)
{
  const int tid  = threadIdx.x;
  const int lane = tid & 63;
  const int wv   = tid >> 6;
  const int il   = lane & 15;
  const int rg   = lane >> 4;
  const int bg   = blockIdx.x & 15;
  const int m    = blockIdx.x >> 4;

  __shared__ __align__(16) uint16_t h_stage[2][8][64][8];   // 16 KB (parity)

  // rec B-frags in VGPR, own-first static slots (R7 lesson / rule #20):
  // kk<4: kt = m*4+kk (own half), kk>=4: peer half.
  short8 wf[4][8];
  #pragma unroll
  for (int q = 0; q < 4; ++q) {
    const int gcol = q * U_ + m * 128 + wv * 16 + il;
    #pragma unroll
    for (int kk = 0; kk < 8; ++kk) {
      const int ktg = ((kk & 4) ? (m ^ 1) : m) * 4 + (kk & 3);
      short8 v;
      #pragma unroll
      for (int j = 0; j < 8; ++j)
        v[j] = (short)f2bf(rker[(size_t)(ktg * 32 + rg * 8 + j) * G4U + gcol]);
      wf[q][kk] = v;
    }
  }

  const int u_loc = wv * 16 + il;
  const int Ua  = m * 128 + u_loc;
  const int kta = Ua >> 5, ga = ((Ua & 31) >> 3) * 16, posa = Ua & 7;

  ull* const pub_s = hbuf + (size_t)(bg * 2 + m) * 2048;
  const ull* const pub_p = hbuf + (size_t)(bg * 2 + (m ^ 1)) * 2048;

  // unpack role (peer/own restore): thread owns unit U*, rows (tid&3)*4..+3
  const int up_u = tid >> 2;
  const int up_rb = (tid & 3) * 4;

  float cst[4];
  if (t0 == 0) {
    #pragma unroll
    for (int j = 0; j < 4; ++j) cst[j] = 0.f;
  } else {
    #pragma unroll
    for (int j = 0; j < 4; ++j)
      cst[j] = cstbuf[(size_t)(bg * 16 + rg * 4 + j) * U_ + Ua];
    // restore OWN half of h_{t0-1} from our own publishes (prev dispatch)
    const ull* op = pub_s + (size_t)((t0 - 1) & 1) * 1024 + tid * 2;
    const ull o0 = ald(op), o1 = ald(op + 1);
    const int U  = m * 128 + up_u;
    const int kt = U >> 5, g = ((U & 31) >> 3) * 16, pos = U & 7;
    h_stage[(t0 - 1) & 1][kt][g + up_rb + 0][pos] = (uint16_t)o0;
    h_stage[(t0 - 1) & 1][kt][g + up_rb + 1][pos] = (uint16_t)(o0 >> 16);
    h_stage[(t0 - 1) & 1][kt][g + up_rb + 2][pos] = (uint16_t)o1;
    h_stage[(t0 - 1) & 1][kt][g + up_rb + 3][pos] = (uint16_t)(o1 >> 16);
  }
  __syncthreads();

  // per-wave xz pointer: wd = m*8 + wv
  const uint16_t* const pzbase = xz + (size_t)bg * L * 16384
                               + (size_t)((m * 8 + wv) * 4) * 256 + lane * 4;
  ull zc[4];
  #pragma unroll
  for (int q = 0; q < 4; ++q) zc[q] = *(const ull*)(pzbase + q * 256);

  for (int tt = 0; tt < L; ++tt) {
    const int t = t0 + tt;
    // (A) issue peer poll loads EARLY
    const ull* pp = pub_p + (size_t)((t - 1) & 1) * 1024 + tid * 2;
    ull pv0 = 0, pv1 = 0;
    if (t > 0) {
      pv0 = ald(pp); pv1 = ald(pp + 1);
      __builtin_amdgcn_sched_barrier(0);
    }
    // (B) acc <- xz unpack (proven-free)
    f32x4 acc[4];
    #pragma unroll
    for (int q = 0; q < 4; ++q) {
      const uint32_t lo = (uint32_t)zc[q];
      const uint32_t hi = (uint32_t)(zc[q] >> 32);
      acc[q][0] = bf2f(lo); acc[q][1] = bf2f(lo >> 16);
      acc[q][2] = bf2f(hi); acc[q][3] = bf2f(hi >> 16);
    }
    // prefetch xz for t+1 (lead ~= one full step)
    {
      const int ntt = (tt + 1 < L) ? tt + 1 : tt;
      const uint16_t* pn = pzbase + (size_t)ntt * 16384;
      #pragma unroll
      for (int q = 0; q < 4; ++q) zc[q] = *(const ull*)(pn + q * 256);
    }
    if (t > 0) {
      // (C) OWN-half rec (h written locally / restored; barrier'd)
      const int p_ = (t - 1) & 1;
      #pragma unroll
      for (int kk = 0; kk < 4; ++kk) {
        short8 a = *(const short8*)&h_stage[p_][m * 4 + kk][lane][0];
        #pragma unroll
        for (int q = 0; q < 4; ++q)
          acc[q] = __builtin_amdgcn_mfma_f32_16x16x32_bf16(a, wf[q][kk], acc[q], 0, 0, 0);
      }
      // (D) poll wait + unpack peer half
      const uint32_t expt = (uint32_t)t;
      while (((uint32_t)(pv0 >> 32) != expt) | ((uint32_t)(pv1 >> 32) != expt)) {
        pv0 = ald(pp); pv1 = ald(pp + 1);
      }
      const int U  = (m ^ 1) * 128 + up_u;
      const int kt = U >> 5, g = ((U & 31) >> 3) * 16, pos = U & 7;
      h_stage[p_][kt][g + up_rb + 0][pos] = (uint16_t)pv0;
      h_stage[p_][kt][g + up_rb + 1][pos] = (uint16_t)(pv0 >> 16);
      h_stage[p_][kt][g + up_rb + 2][pos] = (uint16_t)pv1;
      h_stage[p_][kt][g + up_rb + 3][pos] = (uint16_t)(pv1 >> 16);
    }
    BARRIER_LDS();   // (BAR-M) peer h_stage ready
    if (t > 0) {
      // (E) PEER-half rec
      const int p_ = (t - 1) & 1;
      #pragma unroll
      for (int kk = 0; kk < 4; ++kk) {
        short8 a = *(const short8*)&h_stage[p_][(m ^ 1) * 4 + kk][lane][0];
        #pragma unroll
        for (int q = 0; q < 4; ++q)
          acc[q] = __builtin_amdgcn_mfma_f32_16x16x32_bf16(a, wf[q][4 + kk], acc[q], 0, 0, 0);
      }
    }
    // (F) gates + tagged publish + own-h -> LDS + seq
    {
      uint16_t b16[4];
      #pragma unroll
      for (int j = 0; j < 4; ++j) {
        const float zi = acc[0][j], zf = acc[1][j];
        const float zg = acc[2][j], zo = acc[3][j];
        const float ii = sigm(zi), ff = sigm(zf);
        const float gg = zg * sigm(zg), oo = sigm(zo);
        const float c  = ff * cst[j] + ii * gg;
        cst[j] = c;
        b16[j] = f2bf(oo * (c * sigm(c)));
      }
      const int s2 = t & 1;
      ull* pw = pub_s + (size_t)s2 * 1024 + (size_t)u_loc * 8 + rg * 2;
      const ull tg = (ull)(uint32_t)(t + 1) << 32;
      __hip_atomic_store(pw,     (ull)((uint32_t)b16[0] | ((uint32_t)b16[1] << 16)) | tg,
                         __ATOMIC_RELAXED, __HIP_MEMORY_SCOPE_AGENT);
      __hip_atomic_store(pw + 1, (ull)((uint32_t)b16[2] | ((uint32_t)b16[3] << 16)) | tg,
                         __ATOMIC_RELAXED, __HIP_MEMORY_SCOPE_AGENT);
      #pragma unroll
      for (int j = 0; j < 4; ++j) {
        h_stage[s2][kta][ga + rg * 4 + j][posa] = b16[j];
        seq[((size_t)(bg * 16 + rg * 4 + j) * T_ + t) * U_ + Ua] = b16[j];
      }
    }
    BARRIER_LDS();   // (BAR-E) own-h visible for next step
  }
  // phase epilogue: checkpoint cst (h persists in hbuf publishes)
  #pragma unroll
  for (int j = 0; j < 4; ++j)
    cstbuf[(size_t)(bg * 16 + rg * 4 + j) * U_ + Ua] = cst[j];
}

// ---------------------------------------------------------------------------
// Fallback (ws too small): R8's verified pairwise kernel (full T, fused x).
// ---------------------------------------------------------------------------
__global__ __launch_bounds__(512, 2) void lstm_fallback(
    const float* __restrict__ x, const float* __restrict__ kern,
    const float* __restrict__ rker, const float* __restrict__ bias,
    uint16_t* __restrict__ seq, ull* __restrict__ hbuf)
{
  const int tid  = threadIdx.x;
  const int lane = tid & 63;
  const int wv   = tid >> 6;
  const int il   = lane & 15;
  const int rg   = lane >> 4;
  const int bg   = blockIdx.x & 15;
  const int m    = blockIdx.x >> 4;

  __shared__ __align__(16) uint16_t x_stage[4][64][8];
  __shared__ __align__(16) uint16_t h_stage[2][8][64][8];
  __shared__ __align__(16) uint16_t kern_lds[8192 * 8];

  short8 wf[4][8];
  float  bias_r[4];
  #pragma unroll
  for (int q = 0; q < 4; ++q) {
    const int gcol = q * U_ + m * 128 + wv * 16 + il;
    bias_r[q] = bias[gcol];
    #pragma unroll
    for (int kk = 0; kk < 8; ++kk) {
      const int ktg = ((kk & 4) ? (m ^ 1) : m) * 4 + (kk & 3);
      short8 v;
      #pragma unroll
      for (int j = 0; j < 8; ++j)
        v[j] = (short)f2bf(rker[(size_t)(ktg * 32 + rg * 8 + j) * G4U + gcol]);
      wf[q][kk] = v;
    }
  }
  for (int s = 0; s < 16; ++s) {
    const int slot = tid + s * 512;
    const int ln = slot & 63, kt = (slot >> 6) & 3, ct = slot >> 8;
    const int col = (ct >> 3) * U_ + m * 128 + (ct & 7) * 16 + (ln & 15);
    const int kb  = kt * 32 + (ln >> 4) * 8;
    short8 v;
    #pragma unroll
    for (int j = 0; j < 8; ++j)
      v[j] = (short)f2bf(kern[(size_t)(kb + j) * G4U + col]);
    *(short8*)&kern_lds[(size_t)slot * 8] = v;
  }
  const int xkt = tid >> 7;
  const int xln = (tid >> 1) & 63;
  const int xj0 = (tid & 1) * 4;
  const int xrow = xln & 15;
  const int xk0  = xkt * 32 + (xln >> 4) * 8 + xj0;
  const int Ua  = m * 128 + wv * 16 + il;
  const int kta = Ua >> 5, ga = ((Ua & 31) >> 3) * 16, posa = Ua & 7;
  ull* const pub_s = hbuf + (size_t)(bg * 2 + m) * 2048;
  const ull* const pub_p = hbuf + (size_t)(bg * 2 + (m ^ 1)) * 2048;
  float cst[4];
  #pragma unroll
  for (int j = 0; j < 4; ++j) cst[j] = 0.f;
  float xp[4];
  {
    const float* p = x + ((size_t)(bg * 16 + xrow) * T_ + 0) * F_ + xk0;
    #pragma unroll
    for (int j = 0; j < 4; ++j) xp[j] = p[j];
    uint16_t* d = (uint16_t*)x_stage + tid * 4;
    #pragma unroll
    for (int j = 0; j < 4; ++j) d[j] = f2bf(xp[j]);
  }
  __syncthreads();
  for (int t = 0; t < T_; ++t) {
    const ull* pp = pub_p + (size_t)((t - 1) & 1) * 1024 + tid * 2;
    ull pv0 = 0, pv1 = 0;
    if (t > 0) {
      pv0 = ald(pp); pv1 = ald(pp + 1);
      __builtin_amdgcn_sched_barrier(0);
    }
    {
      const int tn = (t + 1 < T_) ? t + 1 : t;
      const float* p = x + ((size_t)(bg * 16 + xrow) * T_ + tn) * F_ + xk0;
      #pragma unroll
      for (int j = 0; j < 4; ++j) xp[j] = p[j];
    }
    f32x4 acc[4];
    #pragma unroll
    for (int q = 0; q < 4; ++q)
      acc[q] = (f32x4){bias_r[q], bias_r[q], bias_r[q], bias_r[q]};
    #pragma unroll
    for (int kt = 0; kt < 4; ++kt) {
      short8 a = *(const short8*)&x_stage[kt][lane][0];
      #pragma unroll
      for (int q = 0; q < 4; ++q) {
        short8 b = *(const short8*)&kern_lds[(size_t)(((q * 8 + wv) * 4 + kt) * 64 + lane) * 8];
        acc[q] = __builtin_amdgcn_mfma_f32_16x16x32_bf16(a, b, acc[q], 0, 0, 0);
      }
    }
    if (t > 0) {
      const int p_ = (t - 1) & 1;
      #pragma unroll
      for (int kk = 0; kk < 4; ++kk) {
        short8 a = *(const short8*)&h_stage[p_][m * 4 + kk][lane][0];
        #pragma unroll
        for (int q = 0; q < 4; ++q)
          acc[q] = __builtin_amdgcn_mfma_f32_16x16x32_bf16(a, wf[q][kk], acc[q], 0, 0, 0);
      }
      const uint32_t expt = (uint32_t)t;
      while (((uint32_t)(pv0 >> 32) != expt) | ((uint32_t)(pv1 >> 32) != expt)) {
        pv0 = ald(pp); pv1 = ald(pp + 1);
      }
      const int u_loc = tid >> 2;
      const int U  = (m ^ 1) * 128 + u_loc;
      const int kt = U >> 5, g = ((U & 31) >> 3) * 16, pos = U & 7;
      const int rb = (tid & 3) * 4;
      h_stage[p_][kt][g + rb + 0][pos] = (uint16_t)pv0;
      h_stage[p_][kt][g + rb + 1][pos] = (uint16_t)(pv0 >> 16);
      h_stage[p_][kt][g + rb + 2][pos] = (uint16_t)pv1;
      h_stage[p_][kt][g + rb + 3][pos] = (uint16_t)(pv1 >> 16);
    }
    BARRIER_LDS();
    if (t > 0) {
      const int p_ = (t - 1) & 1;
      #pragma unroll
      for (int kk = 0; kk < 4; ++kk) {
        short8 a = *(const short8*)&h_stage[p_][(m ^ 1) * 4 + kk][lane][0];
        #pragma unroll
        for (int q = 0; q < 4; ++q)
          acc[q] = __builtin_amdgcn_mfma_f32_16x16x32_bf16(a, wf[q][4 + kk], acc[q], 0, 0, 0);
      }
    }
    {
      uint16_t* d = (uint16_t*)x_stage + tid * 4;
      #pragma unroll
      for (int j = 0; j < 4; ++j) d[j] = f2bf(xp[j]);
    }
    {
      uint16_t b16[4];
      #pragma unroll
      for (int j = 0; j < 4; ++j) {
        const float zi = acc[0][j], zf = acc[1][j];
        const float zg = acc[2][j], zo = acc[3][j];
        const float ii = sigm(zi), ff = sigm(zf);
        const float gg = zg * sigm(zg), oo = sigm(zo);
        const float c  = ff * cst[j] + ii * gg;
        cst[j] = c;
        b16[j] = f2bf(oo * (c * sigm(c)));
      }
      const int s2 = t & 1;
      ull* pw = pub_s + (size_t)s2 * 1024 + (size_t)(wv * 16 + il) * 8 + rg * 2;
      const ull tg = (ull)(uint32_t)(t + 1) << 32;
      __hip_atomic_store(pw,     (ull)((uint32_t)b16[0] | ((uint32_t)b16[1] << 16)) | tg,
                         __ATOMIC_RELAXED, __HIP_MEMORY_SCOPE_AGENT);
      __hip_atomic_store(pw + 1, (ull)((uint32_t)b16[2] | ((uint32_t)b16[3] << 16)) | tg,
                         __ATOMIC_RELAXED, __HIP_MEMORY_SCOPE_AGENT);
      #pragma unroll
      for (int j = 0; j < 4; ++j) {
        h_stage[s2][kta][ga + rg * 4 + j][posa] = b16[j];
        seq[((size_t)(bg * 16 + rg * 4 + j) * T_ + t) * U_ + Ua] = b16[j];
      }
    }
    BARRIER_LDS();
  }
}

// ---------------------------------------------------------------------------
// Head GEMM + reduce (unchanged, verified).
// ---------------------------------------------------------------------------
__global__ __launch_bounds__(256, 1) void head_kernel(
    const uint16_t* __restrict__ seq, const float* __restrict__ w_out,
    float* __restrict__ partials)
{
  const int g    = blockIdx.x;
  const int tid  = threadIdx.x;
  const int lane = tid & 63;
  const int wv   = tid >> 6;

  f32x4 acc[4][4];
  #pragma unroll
  for (int i = 0; i < 4; ++i)
    #pragma unroll
    for (int c = 0; c < 4; ++c) acc[i][c] = (f32x4){0.f, 0.f, 0.f, 0.f};

  for (int ks = 0; ks < 64; ++ks) {
    const int krow = g * 2048 + ks * 32 + (lane >> 4) * 8;
    short8 bf[4];
    #pragma unroll
    for (int c = 0; c < 4; ++c) {
      short8 v;
      #pragma unroll
      for (int j = 0; j < 8; ++j)
        v[j] = (short)f2bf(w_out[(size_t)(krow + j) * H_ + c * 16 + (lane & 15)]);
      bf[c] = v;
    }
    #pragma unroll
    for (int i = 0; i < 4; ++i) {
      const int b = (wv * 4 + i) * 16 + (lane & 15);
      short8 a = *(const short8*)(seq + (size_t)b * (T_ * U_) + krow);
      #pragma unroll
      for (int c = 0; c < 4; ++c)
        acc[i][c] = __builtin_amdgcn_mfma_f32_16x16x32_bf16(a, bf[c], acc[i][c], 0, 0, 0);
    }
  }
  #pragma unroll
  for (int i = 0; i < 4; ++i)
    #pragma unroll
    for (int c = 0; c < 4; ++c)
      #pragma unroll
      for (int r = 0; r < 4; ++r) {
        const int b = wv * 64 + i * 16 + (lane >> 4) * 4 + r;
        partials[((size_t)g * B_ + b) * H_ + c * 16 + (lane & 15)] = acc[i][c][r];
      }
}

__global__ void reduce_kernel(const float* __restrict__ partials,
                              const float* __restrict__ b_out,
                              float* __restrict__ out)
{
  const int i = blockIdx.x * 256 + threadIdx.x;
  float s = b_out[i & (H_ - 1)];
  #pragma unroll 8
  for (int g = 0; g < 64; ++g) s += partials[(size_t)g * (B_ * H_) + i];
  out[i] = s;
}

// ---------------------------------------------------------------------------
extern "C" void kernel_launch(void* const* d_in, const int* in_sizes, int n_in,
                              void* d_out, int out_size, void* d_ws, size_t ws_size,
                              hipStream_t stream) {
  (void)in_sizes; (void)n_in; (void)out_size;
  const float* x     = (const float*)d_in[0];
  const float* kern  = (const float*)d_in[1];
  const float* rker  = (const float*)d_in[2];
  const float* bias  = (const float*)d_in[3];
  const float* w_out = (const float*)d_in[4];
  const float* b_out = (const float*)d_in[5];
  float* out = (float*)d_out;

  char* ws = (char*)d_ws;
  const size_t seq_bytes  = (size_t)B_ * T_ * U_ * 2;    // 64 MB
  const size_t hbuf_bytes = (size_t)32 * 2048 * 8;       // 512 KB (tags)
  const size_t part_bytes = (size_t)64 * B_ * H_ * 4;    // 4 MB
  const size_t cst_bytes  = (size_t)B_ * U_ * 4;         // 256 KB
  uint16_t* seq      = (uint16_t*)ws;
  ull*      hbuf     = (ull*)(ws + seq_bytes);
  float*    partials = (float*)(ws + seq_bytes + hbuf_bytes);
  float*    cstbuf   = (float*)(ws + seq_bytes + hbuf_bytes + part_bytes);
  const size_t xz_off = seq_bytes + hbuf_bytes + part_bytes + cst_bytes;
  uint16_t* xzbuf = (uint16_t*)(ws + xz_off);

  // largest phase length whose bf16 xz tile fits: xz(L) = L/2 MB
  int L = 0;
  const int cand[4] = {128, 64, 32, 16};
  for (int i = 0; i < 4; ++i) {
    if (ws_size >= xz_off + (size_t)cand[i] * 524288) { L = cand[i]; break; }
  }

  // tag re-init each launch (tags cycle 1..512 across graph replays)
  hipMemsetAsync(hbuf, 0, hbuf_bytes, stream);

  if (L > 0) {
    for (int t0 = 0; t0 < T_; t0 += L) {
      xz_pre<<<2 * L, 256, 0, stream>>>(x, kern, bias, xzbuf, t0, L);
      lstm_pair<<<32, 512, 0, stream>>>(rker, seq, hbuf, xzbuf, cstbuf, t0, L);
    }
  } else {
    lstm_fallback<<<32, 512, 0, stream>>>(x, kern, rker, bias, seq, hbuf);
  }
  head_kernel<<<64, 256, 0, stream>>>(seq, w_out, partials);
  reduce_kernel<<<64, 256, 0, stream>>>(partials, b_out, out);
}